// Round 8
// baseline (253.069 us; speedup 1.0000x reference)
//
#include <hip/hip_runtime.h>
#include <hip/hip_bf16.h>

typedef unsigned short u16;
typedef short s16x8 __attribute__((ext_vector_type(8)));
typedef float f32x4 __attribute__((ext_vector_type(4)));
typedef unsigned short u16x8 __attribute__((ext_vector_type(8)));

#define B_   8
#define N_   24000
#define M_   6000
#define K_   32
#define CIN  64
#define CMID 128
#define COUT 256
#define KP1  96    // 67 zero-padded to 3x32 for MFMA K-steps
#define QB_  188   // ceil(M/32) query-blocks per (batch, quarter) combo

// Static device globals — no ws_size assumption, graph-capture safe,
// fully rewritten on every call. Weights in MFMA fragment order.
__device__ __align__(16) u16 g_W1f[CMID * KP1];                 // 24.6 KB bf16
__device__ __align__(16) u16 g_W2f[COUT * CMID];                // 65.5 KB bf16
__device__ __align__(16) u16 g_Yf[(size_t)B_ * N_ * COUT];      // 98.3 MB bf16

__device__ __forceinline__ float bf2f(u16 u) {
    return __uint_as_float(((unsigned)u) << 16);
}
__device__ __forceinline__ u16 f2bf(float f) {  // fp32 -> bf16 RNE (scalar)
    unsigned u = __float_as_uint(f);
    u += 0x7FFFu + ((u >> 16) & 1u);
    return (u16)(u >> 16);
}
// packed fp32 pair -> 2x bf16 (RNE) in one u32; compiler emits
// v_cvt_pk_bf16_f32 (do NOT hand-write asm — m240). Bit-identical to f2bf.
__device__ __forceinline__ unsigned f2bf2(float lo, float hi) {
    __hip_bfloat162 h = __float22bfloat162_rn(make_float2(lo, hi));
    unsigned r;
    __builtin_memcpy(&r, &h, 4);
    return r;   // lo in bits[15:0], hi in bits[31:16]
}

// ---------------------------------------------------------------------------
// Kernel 0: convert fp32 weights to bf16 in fragment order. (unchanged)
// ---------------------------------------------------------------------------
__global__ void prep_weights(const float* __restrict__ W1,
                             const float* __restrict__ W2) {
    int t = blockIdx.x * 256 + threadIdx.x;   // 0..45055
    if (t < CMID * KP1) {                     // 12288 -> W1f
        int blk = t >> 9, off = t & 511;
        int L = off >> 3, j = off & 7;
        int ln = L & 15, quad = L >> 4;
        int w = blk / 6, r = blk % 6;
        int k0i = r >> 1, mt = r & 1;
        int row = w * 32 + mt * 16 + ln;
        int col = k0i * 32 + quad * 8 + j;
        g_W1f[t] = (col < 67) ? f2bf(W1[row * 67 + col]) : (u16)0;
    } else {                                  // 32768 -> W2f
        int i = t - CMID * KP1;
        int blk = i >> 9, off = i & 511;
        int L = off >> 3, j = off & 7;
        int ln = L & 15, quad = L >> 4;
        int w = blk >> 4, r = blk & 15;
        int k0i = r >> 2, mt = r & 3;
        int row = w * 64 + mt * 16 + ln;
        int col = k0i * 32 + quad * 8 + j;
        g_W2f[i] = f2bf(W2[row * 128 + col]);
    }
}

// ---------------------------------------------------------------------------
// Kernel 1: fused conv1+relu+conv2+relu, v3 — BYTE-IDENTICAL to R14.
// R15 MEASUREMENT ROUND: two blind conv theories (cvt_pk VALU; prefetch +
// conflict-free staging) each bought only ~3-4 us. Residual accounting puts
// conv at ~100-115 us vs a ~25-30 us resource budget (MFMA 8.6, LDS ~8,
// HBM 147MB ~23, VALU ~4) — a 4x gap, cause UNKNOWN because conv has never
// surfaced in the top-5 counter table (gather's 107-us dispatches crowd it
// out). This round splits gather into two ~54-us dispatches so conv tops
// the table and yields its first real counters (MfmaUtil/VALUBusy/Occupancy/
// VGPR/FETCH/WRITE). Discriminator for next round's edit:
//   Occupancy <25%  -> VGPR-bound  -> drop reg-prefetch, launch_bounds cap
//   Occupancy >=40% + low Mfma+VALU -> exposed serial chain -> restructure
//     (skip Hs LDS round-trip via in-register repack / bigger tiles).
// ---------------------------------------------------------------------------
__global__ __launch_bounds__(256) void conv_fused(
        const float* __restrict__ feat, const float* __restrict__ xyz,
        const float* __restrict__ b1,  const float* __restrict__ b2) {
    __shared__ __align__(16) u16 sm[16896];
    u16* Xs = sm;
    u16* Hs = sm + 6656;
    u16* Ys = sm;

    const int tid  = threadIdx.x;
    const int b    = blockIdx.y;
    const int w    = tid >> 6;
    const int L    = tid & 63;
    const int ln   = L & 15;
    const int quad = L >> 4;
    const int p    = L;          // point within tile (staging role)
    const int cg   = w;          // channel group 0..3 (staging role)

    const float* fbase = feat + (size_t)(b * CIN + cg * 16) * N_;

    float raw[16];
    float px = 0.f, py = 0.f, pz = 0.f;

    // prefetch tile 0
    {
        const int n0 = blockIdx.x * 192;
#pragma unroll
        for (int jj = 0; jj < 16; ++jj)
            raw[jj] = fbase[(size_t)jj * N_ + n0 + p];
        if (cg == 0) {
            const float* s = xyz + (size_t)(b * N_ + n0 + p) * 3;
            px = s[0]; py = s[1]; pz = s[2];
        }
    }

    for (int t = 0; t < 3; ++t) {
        const int n0 = blockIdx.x * 192 + t * 64;

        // ---- stage regs -> Xs (conflict-free b128 writes) ----
        {
            u16* dst = Xs + p * 104 + cg * 16;
            uint4 w0, w1;
            w0.x = f2bf2(raw[0],  raw[1]);  w0.y = f2bf2(raw[2],  raw[3]);
            w0.z = f2bf2(raw[4],  raw[5]);  w0.w = f2bf2(raw[6],  raw[7]);
            w1.x = f2bf2(raw[8],  raw[9]);  w1.y = f2bf2(raw[10], raw[11]);
            w1.z = f2bf2(raw[12], raw[13]); w1.w = f2bf2(raw[14], raw[15]);
            *(uint4*)dst = w0;
            *(uint4*)(dst + 8) = w1;
            if (cg == 0) {   // channels 64..95: xyz + zero pad
                u16* xr = Xs + p * 104 + 64;
                uint4 z4; z4.x = f2bf2(px, py); z4.y = f2bf2(pz, 0.f);
                z4.z = 0u; z4.w = 0u;
                uint4 zz; zz.x = zz.y = zz.z = zz.w = 0u;
                *(uint4*)xr = z4;
                *(uint4*)(xr + 8)  = zz;
                *(uint4*)(xr + 16) = zz;
                *(uint4*)(xr + 24) = zz;
            }
        }
        __syncthreads();

        // ---- prefetch next tile (lands under conv1+conv2+out) ----
        if (t < 2) {
            const int n1 = n0 + 64;
#pragma unroll
            for (int jj = 0; jj < 16; ++jj)
                raw[jj] = fbase[(size_t)jj * N_ + n1 + p];
            if (cg == 0) {
                const float* s = xyz + (size_t)(b * N_ + n1 + p) * 3;
                px = s[0]; py = s[1]; pz = s[2];
            }
        }

        // ---- conv1 ----
        f32x4 acc1[2][4];
#pragma unroll
        for (int mt = 0; mt < 2; ++mt)
#pragma unroll
            for (int nt = 0; nt < 4; ++nt) {
                f32x4 zz = {0.f, 0.f, 0.f, 0.f};
                acc1[mt][nt] = zz;
            }
#pragma unroll
        for (int k0i = 0; k0i < 3; ++k0i) {
            s16x8 af[2], xf[4];
#pragma unroll
            for (int mt = 0; mt < 2; ++mt)
                af[mt] = *(const s16x8*)(g_W1f + (((w * 3 + k0i) * 2 + mt) << 9) + L * 8);
#pragma unroll
            for (int nt = 0; nt < 4; ++nt)
                xf[nt] = *(const s16x8*)(Xs + (nt * 16 + ln) * 104 + k0i * 32 + quad * 8);
#pragma unroll
            for (int mt = 0; mt < 2; ++mt)
#pragma unroll
                for (int nt = 0; nt < 4; ++nt)
                    acc1[mt][nt] = __builtin_amdgcn_mfma_f32_16x16x32_bf16(
                        af[mt], xf[nt], acc1[mt][nt], 0, 0, 0);
        }
#pragma unroll
        for (int mt = 0; mt < 2; ++mt) {
            int m0 = w * 32 + mt * 16 + quad * 4;
            float4 bv = *(const float4*)(b1 + m0);
#pragma unroll
            for (int nt = 0; nt < 4; ++nt) {
                int pp = nt * 16 + ln;
                uint2 hv;
                hv.x = f2bf2(fmaxf(acc1[mt][nt][0] + bv.x, 0.f),
                             fmaxf(acc1[mt][nt][1] + bv.y, 0.f));
                hv.y = f2bf2(fmaxf(acc1[mt][nt][2] + bv.z, 0.f),
                             fmaxf(acc1[mt][nt][3] + bv.w, 0.f));
                *(uint2*)(Hs + pp * 136 + m0) = hv;
            }
        }
        __syncthreads();

        // ---- conv2 ----
        f32x4 acc2[4][4];
#pragma unroll
        for (int mt = 0; mt < 4; ++mt)
#pragma unroll
            for (int nt = 0; nt < 4; ++nt) {
                f32x4 zz = {0.f, 0.f, 0.f, 0.f};
                acc2[mt][nt] = zz;
            }
#pragma unroll
        for (int k0i = 0; k0i < 4; ++k0i) {
            s16x8 af[4], hf[4];
#pragma unroll
            for (int mt = 0; mt < 4; ++mt)
                af[mt] = *(const s16x8*)(g_W2f + (((w * 4 + k0i) * 4 + mt) << 9) + L * 8);
#pragma unroll
            for (int nt = 0; nt < 4; ++nt)
                hf[nt] = *(const s16x8*)(Hs + (nt * 16 + ln) * 136 + k0i * 32 + quad * 8);
#pragma unroll
            for (int mt = 0; mt < 4; ++mt)
#pragma unroll
                for (int nt = 0; nt < 4; ++nt)
                    acc2[mt][nt] = __builtin_amdgcn_mfma_f32_16x16x32_bf16(
                        af[mt], hf[nt], acc2[mt][nt], 0, 0, 0);
        }
        __syncthreads();   // conv2's Hs reads done; Ys (aliases Xs+Hs) writable

        // ---- epilogue 2 -> Ys ----
#pragma unroll
        for (int mt = 0; mt < 4; ++mt) {
            int c0 = w * 64 + mt * 16 + quad * 4;
            float4 bv = *(const float4*)(b2 + c0);
#pragma unroll
            for (int nt = 0; nt < 4; ++nt) {
                int pp = nt * 16 + ln;
                uint2 yv;
                yv.x = f2bf2(fmaxf(acc2[mt][nt][0] + bv.x, 0.f),
                             fmaxf(acc2[mt][nt][1] + bv.y, 0.f));
                yv.y = f2bf2(fmaxf(acc2[mt][nt][2] + bv.z, 0.f),
                             fmaxf(acc2[mt][nt][3] + bv.w, 0.f));
                *(uint2*)(Ys + pp * 264 + c0) = yv;
            }
        }
        __syncthreads();

        // ---- Ys -> g_Yf (coalesced dwordx4) ----
        u16* dstY = g_Yf + ((size_t)b * N_ + n0) * COUT;
#pragma unroll
        for (int i = 0; i < 8; ++i) {
            int g = i * 256 + tid;
            int pp = g >> 5, c16 = g & 31;
            *(uint4*)(dstY + (size_t)pp * COUT + c16 * 8) =
                *(const uint4*)(Ys + pp * 264 + c16 * 8);
        }
        if (t < 2) __syncthreads();   // Ys reads done before next Xs write
    }
}

// ---------------------------------------------------------------------------
// Kernel 2: gather + max — measured-best R2 bucket-sorted version. Identical
// per-block code; now takes a BASE so the grid can be split into two ~54-us
// dispatches (l = base + blockIdx.x), letting conv_fused surface in the
// top-5 counter table. Work partition/mapping unchanged.
// ---------------------------------------------------------------------------
__global__ __launch_bounds__(256) void gather_max(
        const int* __restrict__ nbr, float* __restrict__ out, int base) {
    __shared__ __align__(16) u16 smem[32 * 400];          // 25.6 KB union
    int* sidx  = (int*)smem;                              // [1024] bytes 0..4095
    u16* ssort = smem + 2048;                             // [1024] bytes 4096..6143
    int* soff  = (int*)(smem + 3072);                     // [128]  bytes 6144..6655
    int* scur  = (int*)(smem + 3328);                     // [128]  bytes 6656..7167
    u16* ymax  = smem;                                    // [32*400] post-gather

    const int tid = threadIdx.x;
    const int l   = base + blockIdx.x;
    const int xcd = l & 7;
    const int j   = l >> 3;          // 0..751
    const int cw  = j / QB_;         // combo-within-XCD 0..3
    const int qb  = j % QB_;         // query-block 0..187
    const int combo = cw * 8 + xcd;  // 0..31
    const int b   = combo >> 2;
    const int q   = combo & 3;       // channel quarter (64 ch)
    const int m0  = qb * 32;
    const int row = tid >> 3;        // row owning this thread's 4 staged ints
    const int Mv0 = M_ - m0;
    const int Mv  = Mv0 < 32 ? Mv0 : 32;   // valid rows this block (16 or 32)

    // stage neighbor indices (32 queries x 32 k) + zero bucket counters
    if (row < Mv)
        *(int4*)(sidx + tid * 4) =
            *(const int4*)(nbr + ((size_t)b * M_ + m0) * K_ + tid * 4);
    if (tid < 128) scur[tid] = 0;
    __syncthreads();

    // pass 1: per-row phase histogram (phases 0,1 only; 2 is implied)
    unsigned uu[4];
#pragma unroll
    for (int jj = 0; jj < 4; ++jj) {
        unsigned u = (unsigned)sidx[tid * 4 + jj];
        u = u < (unsigned)N_ ? u : 0u;     // defensive clamp (also garbage rows)
        uu[jj] = u;
        int pp = (int)(u >> 13);           // 0:[0,8192) 1:[8192,16384) 2:rest
        if (pp < 2) atomicAdd(&scur[row * 4 + pp], 1);
    }
    __syncthreads();

    // prefix: bucket offsets; reset cursors to bucket starts
    if (tid < 32) {
        int c0 = scur[tid * 4 + 0], c1 = scur[tid * 4 + 1];
        soff[tid * 4 + 0] = 0;
        soff[tid * 4 + 1] = c0;
        soff[tid * 4 + 2] = c0 + c1;
        soff[tid * 4 + 3] = 32;
        scur[tid * 4 + 0] = 0;
        scur[tid * 4 + 1] = c0;
        scur[tid * 4 + 2] = c0 + c1;
    }
    __syncthreads();

    // pass 2: place indices into phase buckets (order within bucket arbitrary)
#pragma unroll
    for (int jj = 0; jj < 4; ++jj) {
        int pp = (int)(uu[jj] >> 13);
        int pos = atomicAdd(&scur[row * 4 + pp], 1);
        ssort[row * 32 + pos] = (u16)uu[jj];
    }
    __syncthreads();

    const int w  = tid >> 6;         // wave 0..3
    const int L  = tid & 63;
    const int kg = L >> 3;           // k-slot within bucket round
    const int co = L & 7;            // channel octet within quarter
    const u16* base_y = g_Yf + (size_t)b * N_ * COUT + q * 64 + co * 8;

    u16x8 mx[8];
#pragma unroll
    for (int i = 0; i < 8; ++i)
        mx[i] = (u16x8){0, 0, 0, 0, 0, 0, 0, 0};

#pragma unroll
    for (int p = 0; p < 3; ++p) {
#pragma unroll
        for (int h = 0; h < 2; ++h) {          // two row-quads per wave
            int mq[4], beg[4], end[4], last[4];
            u16x8 va[4], vb[4];
            // round 0: 4 independent loads (MLP=4)
#pragma unroll
            for (int s = 0; s < 4; ++s) {
                int ml = w * 8 + h * 4 + s;
                mq[s]  = ml < Mv ? ml : 0;     // dead rows redirect to row 0
                beg[s] = soff[mq[s] * 4 + p];
                end[s] = soff[mq[s] * 4 + p + 1];
                int lt = end[s] - 1;
                last[s] = lt > 0 ? lt : 0;
                int p0 = beg[s] + kg; p0 = p0 < last[s] ? p0 : last[s];
                unsigned i0 = (unsigned)ssort[mq[s] * 32 + p0];
                va[s] = *(const u16x8*)(base_y + (size_t)i0 * COUT);
            }
            // round 1 (duplicate-clamped when bucket <= 8)
#pragma unroll
            for (int s = 0; s < 4; ++s) {
                int p1 = beg[s] + 8 + kg; p1 = p1 < last[s] ? p1 : last[s];
                unsigned i1 = (unsigned)ssort[mq[s] * 32 + p1];
                vb[s] = *(const u16x8*)(base_y + (size_t)i1 * COUT);
            }
#pragma unroll
            for (int s = 0; s < 4; ++s)
                mx[h * 4 + s] = __builtin_elementwise_max(mx[h * 4 + s],
                    __builtin_elementwise_max(va[s], vb[s]));
            // rare tail: bucket > 16 (~2% of row-phases), wave-uniform trip
#pragma unroll
            for (int s = 0; s < 4; ++s) {
                for (int r = beg[s] + 16; r < end[s]; r += 8) {
                    int pq = r + kg; pq = pq < last[s] ? pq : last[s];
                    unsigned ii = (unsigned)ssort[mq[s] * 32 + pq];
                    u16x8 vv = *(const u16x8*)(base_y + (size_t)ii * COUT);
                    mx[h * 4 + s] = __builtin_elementwise_max(mx[h * 4 + s], vv);
                }
            }
        }
    }

    __syncthreads();   // all ssort/soff reads done; ymax aliases that storage

    // reduce across the 8 k-slots (lane bits 3,4,5)
#pragma unroll
    for (int i = 0; i < 8; ++i) {
        int ml = w * 8 + i;
        if (ml < Mv) {
            u16x8 m8 = mx[i];
#pragma unroll
            for (int mask = 8; mask <= 32; mask <<= 1) {
                int4 t = *(int4*)&m8;
                t.x = __shfl_xor(t.x, mask);
                t.y = __shfl_xor(t.y, mask);
                t.z = __shfl_xor(t.z, mask);
                t.w = __shfl_xor(t.w, mask);
                m8 = __builtin_elementwise_max(m8, *(u16x8*)&t);
            }
            if (kg == 0)   // one replicate writes 8 channels, 16B ds_write
                *(u16x8*)(ymax + ml * 400 + co * 8) = m8;
        }
    }
    __syncthreads();

    // transpose + bf16->fp32: out[b][q*64+c][m0..m0+31]
    int valid = Mv;
#pragma unroll
    for (int it = 0; it < 2; ++it) {
        int c  = it * 32 + (tid >> 3);   // local channel 0..63
        int mc = (tid & 7) << 2;
        if (mc + 4 <= valid) {
            float4 v;
            v.x = bf2f(ymax[(mc + 0) * 400 + c]);
            v.y = bf2f(ymax[(mc + 1) * 400 + c]);
            v.z = bf2f(ymax[(mc + 2) * 400 + c]);
            v.w = bf2f(ymax[(mc + 3) * 400 + c]);
            *(float4*)(out + (size_t)(b * COUT + q * 64 + c) * M_ + m0 + mc) = v;
        }
    }
}

extern "C" void kernel_launch(void* const* d_in, const int* in_sizes, int n_in,
                              void* d_out, int out_size, void* d_ws, size_t ws_size,
                              hipStream_t stream) {
    // inputs (all fp32 except neighbor_idx int32):
    // 0=query_xyz(unused) 1=support_xyz 2=features 3=neighbor_idx
    // 4=W1 5=b1 6=W2 7=b2. Output: fp32 [B][C_OUT][M].
    const float* xyz  = (const float*)d_in[1];
    const float* feat = (const float*)d_in[2];
    const int*   nbr  = (const int*)d_in[3];
    const float* W1   = (const float*)d_in[4];
    const float* b1   = (const float*)d_in[5];
    const float* W2   = (const float*)d_in[6];
    const float* b2   = (const float*)d_in[7];
    float* out = (float*)d_out;
    (void)d_ws; (void)ws_size;

    prep_weights<<<176, 256, 0, stream>>>(W1, W2);
    conv_fused<<<dim3(125, B_), 256, 0, stream>>>(feat, xyz, b1, b2);
    gather_max<<<3008, 256, 0, stream>>>(nbr, out, 0);      // first half
    gather_max<<<3008, 256, 0, stream>>>(nbr, out, 3008);   // second half
}